// Round 1
// baseline (155.589 us; speedup 1.0000x reference)
//
#include <hip/hip_runtime.h>
#include <stdint.h>

// Problem constants (match reference file).
constexpr int V    = 200000;
constexpr int F    = 128;
constexpr int KIN  = 64;
constexpr int KSEL = 16;
constexpr int VSEL = 50000;

// One wave (64 lanes) per selected row. 4 waves per block of 256.
__global__ __launch_bounds__(256) void lcr_kernel(
    const float* __restrict__ features,
    const float* __restrict__ distances,
    const int*   __restrict__ nidx,
    const int*   __restrict__ sel_idx,
    float*       __restrict__ out)
{
    const int lane = threadIdx.x & 63;
    const int wave = threadIdx.x >> 6;
    const int row  = blockIdx.x * 4 + wave;       // selected-row id
    if (row >= VSEL) return;

    const int v = sel_idx[row];                   // source vertex

    // Each lane owns one of the 64 neighbor slots.
    const float d  = distances[(size_t)v * KIN + lane];
    const int   ni = nidx     [(size_t)v * KIN + lane];

    // Stable sort key: fp32 >= 0 so bit pattern preserves ordering;
    // low 6 bits = original column for stable tie-break (jnp.argsort stable).
    const uint32_t bits = __float_as_uint(ni < 0 ? 1.0e9f : d);
    uint64_t key = ((uint64_t)bits << 6) | (uint32_t)lane;

    // Bitonic sort of 64 keys across the wave (ascending).
    #pragma unroll
    for (int k = 2; k <= 64; k <<= 1) {
        #pragma unroll
        for (int j = k >> 1; j >= 1; j >>= 1) {
            const uint64_t other = __shfl_xor(key, j, 64);
            const bool lower    = (lane & j) == 0;
            const bool asc      = (lane & k) == 0;   // k=64: always ascending
            const bool take_min = (lower == asc);
            const bool swap     = take_min ? (other < key) : (other > key);
            key = swap ? other : key;
        }
    }

    // Lane i (i < 16) now holds the i-th smallest key; recover its nidx.
    const int col       = (int)(key & 63);
    const int sorted_ni = __shfl(ni, col, 64);

    // Gather 16 feature rows of 128 floats; 64 lanes x float2 = 512 B coalesced.
    const size_t out_base = (size_t)row * (KSEL * F);
    #pragma unroll 4
    for (int kk = 0; kk < KSEL; ++kk) {
        const int idx = __shfl(sorted_ni, kk, 64);
        float2 val;
        if (idx < 0) {
            val.x = 0.0f; val.y = 0.0f;
        } else {
            val = *reinterpret_cast<const float2*>(
                      &features[(size_t)idx * F + lane * 2]);
        }
        *reinterpret_cast<float2*>(&out[out_base + (size_t)kk * F + lane * 2]) = val;
    }
}

extern "C" void kernel_launch(void* const* d_in, const int* in_sizes, int n_in,
                              void* d_out, int out_size, void* d_ws, size_t ws_size,
                              hipStream_t stream)
{
    const float* features  = (const float*)d_in[0];
    const float* distances = (const float*)d_in[1];
    const int*   nidx      = (const int*)  d_in[2];
    const int*   sel_idx   = (const int*)  d_in[3];
    // d_in[4] = K scalar (always 16); hardcoded.
    float* out = (float*)d_out;

    const int rows_per_block = 4;                     // 4 waves of 64
    const int grid = (VSEL + rows_per_block - 1) / rows_per_block;
    lcr_kernel<<<grid, 256, 0, stream>>>(features, distances, nidx, sel_idx, out);
}

// Round 3
// 127.242 us; speedup vs baseline: 1.2228x; 1.2228x over previous
//
#include <hip/hip_runtime.h>
#include <stdint.h>

// Problem constants (match reference file).
constexpr int F    = 128;
constexpr int KIN  = 64;
constexpr int KSEL = 16;
constexpr int VSEL = 50000;

typedef float f32x4 __attribute__((ext_vector_type(4)));

// One wave (64 lanes) per selected row. 4 waves per block of 256.
__global__ __launch_bounds__(256) void lcr_kernel(
    const float* __restrict__ features,
    const float* __restrict__ distances,
    const int*   __restrict__ nidx,
    const int*   __restrict__ sel_idx,
    float*       __restrict__ out)
{
    const int lane = threadIdx.x & 63;
    const int wave = threadIdx.x >> 6;
    const int row  = blockIdx.x * 4 + wave;       // selected-row id
    if (row >= VSEL) return;

    const int v = sel_idx[row];                   // source vertex

    // Each lane owns one of the 64 neighbor slots.
    const float d  = distances[(size_t)v * KIN + lane];
    const int   ni = nidx     [(size_t)v * KIN + lane];

    // Stable sort key: fp32 >= 0 so bit pattern preserves ordering;
    // low 6 bits = original column for stable tie-break (jnp.argsort stable).
    const uint32_t bits = __float_as_uint(ni < 0 ? 1.0e9f : d);
    uint64_t key = ((uint64_t)bits << 6) | (uint32_t)lane;

    // Bitonic sort of 64 keys across the wave (ascending).
    #pragma unroll
    for (int k = 2; k <= 64; k <<= 1) {
        #pragma unroll
        for (int j = k >> 1; j >= 1; j >>= 1) {
            const uint64_t other = __shfl_xor(key, j, 64);
            const bool lower    = (lane & j) == 0;
            const bool asc      = (lane & k) == 0;   // k=64: always ascending
            const bool take_min = (lower == asc);
            const bool swap     = take_min ? (other < key) : (other > key);
            key = swap ? other : key;
        }
    }

    // Lane i (i < 16) now holds the i-th smallest key; recover its nidx.
    const int col       = (int)(key & 63);
    const int sorted_ni = __shfl(ni, col, 64);

    // Gather phase: half-wave (32 lanes) per feature row, float4 per lane.
    // 8 unconditional loads in flight (safe-index trick), then 8 NT stores.
    const int half = lane >> 5;                   // which of 2 rows this half handles
    const int l32  = lane & 31;                   // 32 lanes x float4 = 512 B row

    int idxs[8];
    #pragma unroll
    for (int p = 0; p < 8; ++p)
        idxs[p] = __shfl(sorted_ni, 2 * p + half, 64);

    f32x4 vals[8];
    #pragma unroll
    for (int p = 0; p < 8; ++p) {
        const int safe = idxs[p] < 0 ? 0 : idxs[p];
        vals[p] = *reinterpret_cast<const f32x4*>(
                      &features[(size_t)safe * F + l32 * 4]);
    }

    const size_t out_base = (size_t)row * (KSEL * F);
    #pragma unroll
    for (int p = 0; p < 8; ++p) {
        f32x4 val = vals[p];
        if (idxs[p] < 0) { val = (f32x4)(0.0f); }
        __builtin_nontemporal_store(val,
            reinterpret_cast<f32x4*>(&out[out_base + (size_t)(2 * p + half) * F + l32 * 4]));
    }
}

extern "C" void kernel_launch(void* const* d_in, const int* in_sizes, int n_in,
                              void* d_out, int out_size, void* d_ws, size_t ws_size,
                              hipStream_t stream)
{
    const float* features  = (const float*)d_in[0];
    const float* distances = (const float*)d_in[1];
    const int*   nidx      = (const int*)  d_in[2];
    const int*   sel_idx   = (const int*)  d_in[3];
    // d_in[4] = K scalar (always 16); hardcoded.
    float* out = (float*)d_out;

    const int rows_per_block = 4;                     // 4 waves of 64
    const int grid = (VSEL + rows_per_block - 1) / rows_per_block;
    lcr_kernel<<<grid, 256, 0, stream>>>(features, distances, nidx, sel_idx, out);
}